// Round 1
// baseline (670.963 us; speedup 1.0000x reference)
//
#include <hip/hip_runtime.h>
#include <hip/hip_bf16.h>

#define N_NODES   100000
#define N_EDGES   1600000
#define FDIM      128
#define N_GRAPHS  1024
#define N_CLASSES 32
#define SCAN_BLK  1024   // elements per scan block

// ---------------------------------------------------------------------------
// degree count: indeg[dst] += 1 per edge
__global__ void k_count(const int* __restrict__ dst, int* __restrict__ indeg, int E) {
    int i = blockIdx.x * blockDim.x + threadIdx.x;
    if (i < E) atomicAdd(&indeg[dst[i]], 1);
}

// dinv[v] = rsqrt(indeg[v] + 1)   (+1 = self loop; always > 0)
__global__ void k_dinv(const int* __restrict__ indeg, float* __restrict__ dinv, int n) {
    int i = blockIdx.x * blockDim.x + threadIdx.x;
    if (i < n) dinv[i] = rsqrtf((float)(indeg[i] + 1));
}

// ---------------------------------------------------------------------------
// exclusive prefix scan of indeg -> rp, 3 kernels
__global__ void k_scan1(const int* __restrict__ in, int* __restrict__ out,
                        int* __restrict__ bsums, int n) {
    __shared__ int lds[256];
    int blk = blockIdx.x, t = threadIdx.x;
    int base = blk * SCAN_BLK + t * 4;
    int v[4];
#pragma unroll
    for (int i = 0; i < 4; ++i) v[i] = (base + i < n) ? in[base + i] : 0;
    int local = v[0] + v[1] + v[2] + v[3];
    lds[t] = local;
    __syncthreads();
    for (int off = 1; off < 256; off <<= 1) {
        int x = lds[t];
        int y = (t >= off) ? lds[t - off] : 0;
        __syncthreads();
        lds[t] = x + y;
        __syncthreads();
    }
    int excl = lds[t] - local;
    if (t == 255) bsums[blk] = lds[255];
    int run = excl;
#pragma unroll
    for (int i = 0; i < 4; ++i) {
        if (base + i < n) { out[base + i] = run; run += v[i]; }
    }
}

__global__ void k_scan2(int* __restrict__ bsums, int nb) {
    __shared__ int lds[256];
    int t = threadIdx.x;
    int orig = (t < nb) ? bsums[t] : 0;
    lds[t] = orig;
    __syncthreads();
    for (int off = 1; off < 256; off <<= 1) {
        int x = lds[t];
        int y = (t >= off) ? lds[t - off] : 0;
        __syncthreads();
        lds[t] = x + y;
        __syncthreads();
    }
    if (t < nb) bsums[t] = lds[t] - orig;   // exclusive
}

__global__ void k_scan3(int* __restrict__ rp, const int* __restrict__ boffs, int n, int E) {
    int i = blockIdx.x * blockDim.x + threadIdx.x;
    if (i < n) rp[i] += boffs[i / SCAN_BLK];
    if (i == n) rp[n] = E;
}

// fill CSR: col[rp[d] + slot] = src
__global__ void k_fill(const int* __restrict__ src, const int* __restrict__ dst,
                       const int* __restrict__ rp, int* __restrict__ cursor,
                       int* __restrict__ col, int E) {
    int i = blockIdx.x * blockDim.x + threadIdx.x;
    if (i < E) {
        int d = dst[i];
        int p = atomicAdd(&cursor[d], 1);
        col[rp[d] + p] = src[i];
    }
}

// ---------------------------------------------------------------------------
// out[v] = dinv[v]^2 * X[v] + sum_{s in N(v)} dinv[v]*dinv[s]*X[s]
__global__ void k_agg(const float* __restrict__ X, float* __restrict__ out,
                      const int* __restrict__ rp, const int* __restrict__ col,
                      const float* __restrict__ dinv) {
    int v = blockIdx.x;
    int j = threadIdx.x;             // 128 threads = one feature each
    float dv = dinv[v];
    float acc = dv * dv * X[(size_t)v * FDIM + j];
    int e0 = rp[v], e1 = rp[v + 1];
    int e = e0;
    for (; e + 1 < e1; e += 2) {
        int s0 = col[e], s1 = col[e + 1];
        float w0 = dv * dinv[s0];
        float w1 = dv * dinv[s1];
        acc += w0 * X[(size_t)s0 * FDIM + j];
        acc += w1 * X[(size_t)s1 * FDIM + j];
    }
    if (e < e1) {
        int s0 = col[e];
        acc += dv * dinv[s0] * X[(size_t)s0 * FDIM + j];
    }
    out[(size_t)v * FDIM + j] = acc;
}

// same aggregation over B, fused with mean-pool accumulation into P / cnt
__global__ void k_agg_pool(const float* __restrict__ X,
                           const int* __restrict__ rp, const int* __restrict__ col,
                           const float* __restrict__ dinv, const int* __restrict__ batch,
                           float* __restrict__ P, int* __restrict__ cnt) {
    int v = blockIdx.x;
    int j = threadIdx.x;
    float dv = dinv[v];
    float acc = dv * dv * X[(size_t)v * FDIM + j];
    int e0 = rp[v], e1 = rp[v + 1];
    int e = e0;
    for (; e + 1 < e1; e += 2) {
        int s0 = col[e], s1 = col[e + 1];
        float w0 = dv * dinv[s0];
        float w1 = dv * dinv[s1];
        acc += w0 * X[(size_t)s0 * FDIM + j];
        acc += w1 * X[(size_t)s1 * FDIM + j];
    }
    if (e < e1) {
        int s0 = col[e];
        acc += dv * dinv[s0] * X[(size_t)s0 * FDIM + j];
    }
    int g = batch[v];
    atomicAdd(&P[(size_t)g * FDIM + j], acc);
    if (j == 0) atomicAdd(&cnt[g], 1);
}

// ---------------------------------------------------------------------------
// B = relu(A @ W + bias), 16 rows per block, W staged in LDS
__global__ __launch_bounds__(256) void k_gemm_relu(const float* __restrict__ A,
                                                   const float* __restrict__ W,
                                                   const float* __restrict__ bias,
                                                   float* __restrict__ B) {
    __shared__ float Ws[128][128];
    __shared__ float As[16][128];
    int t = threadIdx.x;
    for (int i = t; i < 128 * 128; i += 256) Ws[i >> 7][i & 127] = W[i];
    size_t row0 = (size_t)blockIdx.x * 16;
    for (int i = t; i < 16 * 128; i += 256) As[i >> 7][i & 127] = A[row0 * 128 + i];
    __syncthreads();
    int c = t & 127, rg = t >> 7;      // 2 row-groups x 128 cols
    for (int r = rg; r < 16; r += 2) {
        float acc = bias[c];
#pragma unroll
        for (int k = 0; k < 128; ++k) acc = fmaf(As[r][k], Ws[k][c], acc);
        B[(row0 + r) * 128 + c] = fmaxf(acc, 0.0f);
    }
}

// Wc = W2 @ Wf  [128,32];  bc = b2 @ Wf + bf  [32]
__global__ void k_wcomb(const float* __restrict__ W2, const float* __restrict__ Wf,
                        const float* __restrict__ b2, const float* __restrict__ bf,
                        float* __restrict__ Wc, float* __restrict__ bc) {
    int idx = blockIdx.x * blockDim.x + threadIdx.x;
    if (idx < 128 * 32) {
        int k = idx >> 5, c = idx & 31;
        float acc = 0.0f;
        for (int m = 0; m < 128; ++m) acc += W2[k * 128 + m] * Wf[m * 32 + c];
        Wc[idx] = acc;
    }
    if (idx < 32) {
        float acc = bf[idx];
        for (int m = 0; m < 128; ++m) acc += b2[m] * Wf[m * 32 + idx];
        bc[idx] = acc;
    }
}

// out[g] = (P[g]/cnt[g]) @ Wc + bc    (cnt==0 -> bf, matching clip semantics)
__global__ void k_final(const float* __restrict__ P, const int* __restrict__ cnt,
                        const float* __restrict__ Wc, const float* __restrict__ bc,
                        const float* __restrict__ bf, float* __restrict__ out) {
    __shared__ float p[128];
    int g = blockIdx.x, t = threadIdx.x;
    int c_ = cnt[g];
    float inv = (c_ > 0) ? 1.0f / (float)c_ : 0.0f;
    p[t] = P[(size_t)g * FDIM + t] * inv;
    __syncthreads();
    if (t < N_CLASSES) {
        float acc = (c_ > 0) ? bc[t] : bf[t];
#pragma unroll
        for (int k = 0; k < 128; ++k) acc = fmaf(p[k], Wc[k * 32 + t], acc);
        out[(size_t)g * N_CLASSES + t] = acc;
    }
}

// ---------------------------------------------------------------------------
extern "C" void kernel_launch(void* const* d_in, const int* in_sizes, int n_in,
                              void* d_out, int out_size, void* d_ws, size_t ws_size,
                              hipStream_t stream) {
    const float* x    = (const float*)d_in[0];
    const int*   ei   = (const int*)d_in[1];
    const int*   batch= (const int*)d_in[2];
    const float* W1   = (const float*)d_in[3];
    const float* b1   = (const float*)d_in[4];
    const float* W2   = (const float*)d_in[5];
    const float* b2   = (const float*)d_in[6];
    const float* Wf   = (const float*)d_in[7];
    const float* bf   = (const float*)d_in[8];
    const int* src = ei;
    const int* dst = ei + N_EDGES;

    char* w = (char*)d_ws;
    auto alloc = [&](size_t bytes) { char* p = w; w += (bytes + 255) & ~255ull; return p; };
    int*   indeg  = (int*)  alloc((size_t)N_NODES * 4);
    float* dinv   = (float*)alloc((size_t)N_NODES * 4);
    int*   rp     = (int*)  alloc((size_t)(N_NODES + 1) * 4);
    int*   cursor = (int*)  alloc((size_t)N_NODES * 4);
    int*   bsums  = (int*)  alloc(1024 * 4);
    int*   col    = (int*)  alloc((size_t)N_EDGES * 4);
    float* A      = (float*)alloc((size_t)N_NODES * FDIM * 4);
    float* B      = (float*)alloc((size_t)N_NODES * FDIM * 4);
    float* P      = (float*)alloc((size_t)N_GRAPHS * FDIM * 4);
    int*   cnt    = (int*)  alloc((size_t)N_GRAPHS * 4);
    float* Wc     = (float*)alloc(128 * 32 * 4);
    float* bc     = (float*)alloc(32 * 4);

    hipMemsetAsync(indeg,  0, (size_t)N_NODES * 4, stream);
    hipMemsetAsync(cursor, 0, (size_t)N_NODES * 4, stream);
    hipMemsetAsync(P,      0, (size_t)N_GRAPHS * FDIM * 4, stream);
    hipMemsetAsync(cnt,    0, (size_t)N_GRAPHS * 4, stream);

    const int nbScan = (N_NODES + SCAN_BLK - 1) / SCAN_BLK;   // 98

    k_count<<<(N_EDGES + 255) / 256, 256, 0, stream>>>(dst, indeg, N_EDGES);
    k_dinv <<<(N_NODES + 255) / 256, 256, 0, stream>>>(indeg, dinv, N_NODES);
    k_scan1<<<nbScan, 256, 0, stream>>>(indeg, rp, bsums, N_NODES);
    k_scan2<<<1, 256, 0, stream>>>(bsums, nbScan);
    k_scan3<<<(N_NODES + 1 + 255) / 256, 256, 0, stream>>>(rp, bsums, N_NODES, N_EDGES);
    k_fill <<<(N_EDGES + 255) / 256, 256, 0, stream>>>(src, dst, rp, cursor, col, N_EDGES);

    // layer 1: aggregate x, then GEMM+bias+relu
    k_agg<<<N_NODES, 128, 0, stream>>>(x, A, rp, col, dinv);
    k_gemm_relu<<<N_NODES / 16, 256, 0, stream>>>(A, W1, b1, B);

    // classifier weight folding (independent, tiny)
    k_wcomb<<<16, 256, 0, stream>>>(W2, Wf, b2, bf, Wc, bc);

    // layer 2 aggregation fused with mean-pool accumulation
    k_agg_pool<<<N_NODES, 128, 0, stream>>>(B, rp, col, dinv, batch, P, cnt);

    // final: mean, fold through Wc, write [1024,32]
    k_final<<<N_GRAPHS, 128, 0, stream>>>(P, cnt, Wc, bc, bf, (float*)d_out);
}

// Round 2
// 523.298 us; speedup vs baseline: 1.2822x; 1.2822x over previous
//
#include <hip/hip_runtime.h>
#include <hip/hip_bf16.h>

#define N_NODES   100000
#define N_EDGES   1600000
#define FDIM      128
#define N_GRAPHS  1024
#define N_CLASSES 32
#define SCAN_BLK  1024
#define M_PAD     100032   // N_NODES padded to 64-row multiple for GEMM tiles

typedef __attribute__((ext_vector_type(8))) short short8v;
typedef __attribute__((ext_vector_type(4))) float f32x4;

__device__ __forceinline__ float bflo(unsigned u){ union{unsigned i; float f;} c; c.i = u << 16; return c.f; }
__device__ __forceinline__ float bfhi(unsigned u){ union{unsigned i; float f;} c; c.i = u & 0xffff0000u; return c.f; }
__device__ __forceinline__ unsigned short f2bf(float f){
    union{float f; unsigned u;} c{f};
    return (unsigned short)((c.u + 0x7fffu + ((c.u >> 16) & 1u)) >> 16);
}
__device__ __forceinline__ unsigned packbf2(float a, float b){
    return (unsigned)f2bf(a) | ((unsigned)f2bf(b) << 16);
}

// ---------------------------------------------------------------------------
// fp32 -> packed bf16x2 (n2 = number of float PAIRS)
__global__ void k_f2bf(const float* __restrict__ in, unsigned* __restrict__ out, int n2) {
    int i = blockIdx.x * blockDim.x + threadIdx.x;
    if (i < n2) {
        float2 v = ((const float2*)in)[i];
        out[i] = packbf2(v.x, v.y);
    }
}

// W1 [k][n] fp32 -> Wt [n][k] bf16  (transposed for MFMA B-frag contiguity)
__global__ void k_wt(const float* __restrict__ W, unsigned short* __restrict__ Wt) {
    int i = blockIdx.x * blockDim.x + threadIdx.x;   // 16384
    int k = i >> 7, n = i & 127;
    Wt[n * 128 + k] = f2bf(W[i]);
}

// ---------------------------------------------------------------------------
__global__ void k_count(const int* __restrict__ dst, int* __restrict__ indeg, int E) {
    int i = blockIdx.x * blockDim.x + threadIdx.x;
    if (i < E) atomicAdd(&indeg[dst[i]], 1);
}

__global__ void k_dinv(const int* __restrict__ indeg, float* __restrict__ dinv, int n) {
    int i = blockIdx.x * blockDim.x + threadIdx.x;
    if (i < n) dinv[i] = rsqrtf((float)(indeg[i] + 1));
}

__global__ void k_scan1(const int* __restrict__ in, int* __restrict__ out,
                        int* __restrict__ bsums, int n) {
    __shared__ int lds[256];
    int blk = blockIdx.x, t = threadIdx.x;
    int base = blk * SCAN_BLK + t * 4;
    int v[4];
#pragma unroll
    for (int i = 0; i < 4; ++i) v[i] = (base + i < n) ? in[base + i] : 0;
    int local = v[0] + v[1] + v[2] + v[3];
    lds[t] = local;
    __syncthreads();
    for (int off = 1; off < 256; off <<= 1) {
        int x = lds[t];
        int y = (t >= off) ? lds[t - off] : 0;
        __syncthreads();
        lds[t] = x + y;
        __syncthreads();
    }
    int excl = lds[t] - local;
    if (t == 255) bsums[blk] = lds[255];
    int run = excl;
#pragma unroll
    for (int i = 0; i < 4; ++i) {
        if (base + i < n) { out[base + i] = run; run += v[i]; }
    }
}

__global__ void k_scan2(int* __restrict__ bsums, int nb) {
    __shared__ int lds[256];
    int t = threadIdx.x;
    int orig = (t < nb) ? bsums[t] : 0;
    lds[t] = orig;
    __syncthreads();
    for (int off = 1; off < 256; off <<= 1) {
        int x = lds[t];
        int y = (t >= off) ? lds[t - off] : 0;
        __syncthreads();
        lds[t] = x + y;
        __syncthreads();
    }
    if (t < nb) bsums[t] = lds[t] - orig;
}

__global__ void k_scan3(int* __restrict__ rp, const int* __restrict__ boffs, int n, int E) {
    int i = blockIdx.x * blockDim.x + threadIdx.x;
    if (i < n) rp[i] += boffs[i / SCAN_BLK];
    if (i == n) rp[n] = E;
}

// fill CSR + per-edge normalized weight (kills the col->dinv dependent load)
__global__ void k_fill(const int* __restrict__ src, const int* __restrict__ dst,
                       const int* __restrict__ rp, int* __restrict__ cursor,
                       int* __restrict__ col, float* __restrict__ wgt,
                       const float* __restrict__ dinv, int E) {
    int i = blockIdx.x * blockDim.x + threadIdx.x;
    if (i < E) {
        int d = dst[i], s = src[i];
        int p = atomicAdd(&cursor[d], 1);
        int idx = rp[d] + p;
        col[idx] = s;
        wgt[idx] = dinv[d] * dinv[s];
    }
}

// ---------------------------------------------------------------------------
// gather-aggregate over bf16 rows; one wave per node, lane = feature pair.
// unroll x4 with software-pipelined col/wgt prefetch for MLP depth.
#define AGG_BODY(X2, V)                                                          \
    int lane = threadIdx.x & 63;                                                 \
    int V = (blockIdx.x << 2) + (threadIdx.x >> 6);                              \
    if (V >= N_NODES) return;                                                    \
    float dv = dinv[V];                                                          \
    unsigned xs = X2[V * 64 + lane];                                             \
    float wself = dv * dv;                                                       \
    float a0x = wself * bflo(xs), a0y = wself * bfhi(xs);                        \
    float a1x = 0.f, a1y = 0.f, a2x = 0.f, a2y = 0.f, a3x = 0.f, a3y = 0.f;     \
    int e = rp[V], e1 = rp[V + 1];                                               \
    if (e + 4 <= e1) {                                                           \
        int s0 = col[e], s1 = col[e+1], s2 = col[e+2], s3 = col[e+3];            \
        float w0 = wgt[e], w1 = wgt[e+1], w2 = wgt[e+2], w3 = wgt[e+3];          \
        while (true) {                                                           \
            int en = e + 4;                                                      \
            bool more = (en + 4 <= e1);                                          \
            int t0, t1, t2, t3; float y0, y1, y2, y3;                            \
            if (more) {                                                          \
                t0 = col[en]; t1 = col[en+1]; t2 = col[en+2]; t3 = col[en+3];    \
                y0 = wgt[en]; y1 = wgt[en+1]; y2 = wgt[en+2]; y3 = wgt[en+3];    \
            }                                                                    \
            unsigned u0 = X2[s0*64 + lane], u1 = X2[s1*64 + lane];               \
            unsigned u2 = X2[s2*64 + lane], u3 = X2[s3*64 + lane];               \
            a0x += w0 * bflo(u0); a0y += w0 * bfhi(u0);                          \
            a1x += w1 * bflo(u1); a1y += w1 * bfhi(u1);                          \
            a2x += w2 * bflo(u2); a2y += w2 * bfhi(u2);                          \
            a3x += w3 * bflo(u3); a3y += w3 * bfhi(u3);                          \
            e = en;                                                              \
            if (!more) break;                                                    \
            s0 = t0; s1 = t1; s2 = t2; s3 = t3;                                  \
            w0 = y0; w1 = y1; w2 = y2; w3 = y3;                                  \
        }                                                                        \
    }                                                                            \
    for (; e < e1; ++e) {                                                        \
        int s = col[e]; float w = wgt[e];                                        \
        unsigned u = X2[s*64 + lane];                                            \
        a0x += w * bflo(u); a0y += w * bfhi(u);                                  \
    }                                                                            \
    float ax = (a0x + a1x) + (a2x + a3x);                                        \
    float ay = (a0y + a1y) + (a2y + a3y);

__global__ __launch_bounds__(256) void k_agg1(
    const unsigned* __restrict__ X2, unsigned* __restrict__ O2,
    const int* __restrict__ rp, const int* __restrict__ col,
    const float* __restrict__ wgt, const float* __restrict__ dinv)
{
    AGG_BODY(X2, v)
    O2[v * 64 + lane] = packbf2(ax, ay);
}

__global__ __launch_bounds__(256) void k_agg2(
    const unsigned* __restrict__ X2,
    const int* __restrict__ rp, const int* __restrict__ col,
    const float* __restrict__ wgt, const float* __restrict__ dinv,
    const int* __restrict__ batch, float* __restrict__ P, int* __restrict__ cnt)
{
    AGG_BODY(X2, v)
    int g = batch[v];
    atomicAdd(&P[(size_t)g * FDIM + 2 * lane],     ax);
    atomicAdd(&P[(size_t)g * FDIM + 2 * lane + 1], ay);
    if (lane == 0) atomicAdd(&cnt[g], 1);
}

// ---------------------------------------------------------------------------
// B = relu(A @ W1 + b1) in bf16 via MFMA. Block = 64 rows; wave = 16 rows x 128 cols.
// A-frag: row = lane&15, k = 8*(lane>>4)+j (contiguous).  B-frag from Wt[n][k].
// D: col = lane&15, row = 4*(lane>>4)+i  (verified layout).
__global__ __launch_bounds__(256) void k_gemm_mfma(
    const unsigned short* __restrict__ A, const unsigned short* __restrict__ Wt,
    const float* __restrict__ bias, unsigned short* __restrict__ B)
{
    int lane = threadIdx.x & 63;
    int wv = threadIdx.x >> 6;
    size_t row0 = (size_t)blockIdx.x * 64 + (size_t)wv * 16;
    int r = lane & 15, g = lane >> 4;

    short8v af[4];
    const unsigned short* arow = A + (row0 + r) * FDIM + g * 8;
#pragma unroll
    for (int ks = 0; ks < 4; ++ks)
        af[ks] = *(const short8v*)(arow + ks * 32);

    f32x4 acc[8];
#pragma unroll
    for (int ct = 0; ct < 8; ++ct) {
        f32x4 a = {0.f, 0.f, 0.f, 0.f};
        const unsigned short* wrow = Wt + (ct * 16 + r) * FDIM + g * 8;
#pragma unroll
        for (int ks = 0; ks < 4; ++ks) {
            short8v bfr = *(const short8v*)(wrow + ks * 32);
            a = __builtin_amdgcn_mfma_f32_16x16x32_bf16(af[ks], bfr, a, 0, 0, 0);
        }
        acc[ct] = a;
    }

#pragma unroll
    for (int ct = 0; ct < 8; ++ct) {
        int c = ct * 16 + r;
        float bs = bias[c];
#pragma unroll
        for (int i = 0; i < 4; ++i) {
            size_t row = row0 + g * 4 + i;
            if (row < N_NODES) {
                float vv = fmaxf(acc[ct][i] + bs, 0.f);
                B[row * FDIM + c] = f2bf(vv);
            }
        }
    }
}

// ---------------------------------------------------------------------------
__global__ void k_wcomb(const float* __restrict__ W2, const float* __restrict__ Wf,
                        const float* __restrict__ b2, const float* __restrict__ bf,
                        float* __restrict__ Wc, float* __restrict__ bc) {
    int idx = blockIdx.x * blockDim.x + threadIdx.x;
    if (idx < 128 * 32) {
        int k = idx >> 5, c = idx & 31;
        float acc = 0.0f;
        for (int m = 0; m < 128; ++m) acc += W2[k * 128 + m] * Wf[m * 32 + c];
        Wc[idx] = acc;
    }
    if (idx < 32) {
        float acc = bf[idx];
        for (int m = 0; m < 128; ++m) acc += b2[m] * Wf[m * 32 + idx];
        bc[idx] = acc;
    }
}

__global__ void k_final(const float* __restrict__ P, const int* __restrict__ cnt,
                        const float* __restrict__ Wc, const float* __restrict__ bc,
                        const float* __restrict__ bf, float* __restrict__ out) {
    __shared__ float p[128];
    int g = blockIdx.x, t = threadIdx.x;
    int c_ = cnt[g];
    float inv = (c_ > 0) ? 1.0f / (float)c_ : 0.0f;
    p[t] = P[(size_t)g * FDIM + t] * inv;
    __syncthreads();
    if (t < N_CLASSES) {
        float acc = (c_ > 0) ? bc[t] : bf[t];
#pragma unroll
        for (int k = 0; k < 128; ++k) acc = fmaf(p[k], Wc[k * 32 + t], acc);
        out[(size_t)g * N_CLASSES + t] = acc;
    }
}

// ---------------------------------------------------------------------------
extern "C" void kernel_launch(void* const* d_in, const int* in_sizes, int n_in,
                              void* d_out, int out_size, void* d_ws, size_t ws_size,
                              hipStream_t stream) {
    const float* x    = (const float*)d_in[0];
    const int*   ei   = (const int*)d_in[1];
    const int*   batch= (const int*)d_in[2];
    const float* W1   = (const float*)d_in[3];
    const float* b1   = (const float*)d_in[4];
    const float* W2   = (const float*)d_in[5];
    const float* b2   = (const float*)d_in[6];
    const float* Wf   = (const float*)d_in[7];
    const float* bf   = (const float*)d_in[8];
    const int* src = ei;
    const int* dst = ei + N_EDGES;

    char* w = (char*)d_ws;
    auto alloc = [&](size_t bytes) { char* p = w; w += (bytes + 255) & ~255ull; return p; };
    int*      indeg  = (int*)     alloc((size_t)N_NODES * 4);
    float*    dinv   = (float*)   alloc((size_t)N_NODES * 4);
    int*      rp     = (int*)     alloc((size_t)(N_NODES + 1) * 4);
    int*      cursor = (int*)     alloc((size_t)N_NODES * 4);
    int*      bsums  = (int*)     alloc(1024 * 4);
    int*      col    = (int*)     alloc((size_t)N_EDGES * 4);
    float*    wgt    = (float*)   alloc((size_t)N_EDGES * 4);
    unsigned* xh     = (unsigned*)alloc((size_t)N_NODES * 64 * 4);   // bf16x2
    unsigned* Ab     = (unsigned*)alloc((size_t)M_PAD  * 64 * 4);    // bf16x2 (padded)
    unsigned* Bb     = (unsigned*)alloc((size_t)N_NODES * 64 * 4);   // bf16x2
    unsigned short* Wt = (unsigned short*)alloc(128 * 128 * 2);
    float*    P      = (float*)   alloc((size_t)N_GRAPHS * FDIM * 4);
    int*      cnt    = (int*)     alloc((size_t)N_GRAPHS * 4);
    float*    Wc     = (float*)   alloc(128 * 32 * 4);
    float*    bc     = (float*)   alloc(32 * 4);

    hipMemsetAsync(indeg,  0, (size_t)N_NODES * 4, stream);
    hipMemsetAsync(cursor, 0, (size_t)N_NODES * 4, stream);
    hipMemsetAsync(P,      0, (size_t)N_GRAPHS * FDIM * 4, stream);
    hipMemsetAsync(cnt,    0, (size_t)N_GRAPHS * 4, stream);

    const int nbScan = (N_NODES + SCAN_BLK - 1) / SCAN_BLK;   // 98

    // input conversions (independent of CSR build)
    k_f2bf<<<(N_NODES * 64 + 255) / 256, 256, 0, stream>>>(x, xh, N_NODES * 64);
    k_wt  <<<64, 256, 0, stream>>>(W1, Wt);

    // CSR build
    k_count<<<(N_EDGES + 255) / 256, 256, 0, stream>>>(dst, indeg, N_EDGES);
    k_dinv <<<(N_NODES + 255) / 256, 256, 0, stream>>>(indeg, dinv, N_NODES);
    k_scan1<<<nbScan, 256, 0, stream>>>(indeg, rp, bsums, N_NODES);
    k_scan2<<<1, 256, 0, stream>>>(bsums, nbScan);
    k_scan3<<<(N_NODES + 1 + 255) / 256, 256, 0, stream>>>(rp, bsums, N_NODES, N_EDGES);
    k_fill <<<(N_EDGES + 255) / 256, 256, 0, stream>>>(src, dst, rp, cursor, col, wgt, dinv, N_EDGES);

    // layer 1: aggregate (bf16 gather) then MFMA GEMM + bias + relu
    k_agg1<<<(N_NODES + 3) / 4, 256, 0, stream>>>(xh, Ab, rp, col, wgt, dinv);
    k_gemm_mfma<<<M_PAD / 64, 256, 0, stream>>>((const unsigned short*)Ab, Wt, b1,
                                                (unsigned short*)Bb);

    // classifier weight folding (tiny, independent)
    k_wcomb<<<16, 256, 0, stream>>>(W2, Wf, b2, bf, Wc, bc);

    // layer 2 aggregation fused with mean-pool accumulation
    k_agg2<<<(N_NODES + 3) / 4, 256, 0, stream>>>(Bb, rp, col, wgt, dinv, batch, P, cnt);

    // final: mean, fold through Wc=W2@Wf, write [1024,32]
    k_final<<<N_GRAPHS, 128, 0, stream>>>(P, cnt, Wc, bc, bf, (float*)d_out);
}

// Round 3
// 492.486 us; speedup vs baseline: 1.3624x; 1.0626x over previous
//
#include <hip/hip_runtime.h>
#include <hip/hip_bf16.h>

#define N_NODES   100000
#define N_EDGES   1600000
#define FDIM      128
#define N_GRAPHS  1024
#define N_CLASSES 32
#define SCAN_BLK  1024
#define M_PAD     100032   // N_NODES padded to 64-row multiple for GEMM tiles

typedef __attribute__((ext_vector_type(8))) short short8v;
typedef __attribute__((ext_vector_type(4))) float f32x4;

__device__ __forceinline__ float bflo(unsigned u){ union{unsigned i; float f;} c; c.i = u << 16; return c.f; }
__device__ __forceinline__ float bfhi(unsigned u){ union{unsigned i; float f;} c; c.i = u & 0xffff0000u; return c.f; }
__device__ __forceinline__ unsigned short f2bf(float f){
    union{float f; unsigned u;} c{f};
    return (unsigned short)((c.u + 0x7fffu + ((c.u >> 16) & 1u)) >> 16);
}
__device__ __forceinline__ unsigned packbf2(float a, float b){
    return (unsigned)f2bf(a) | ((unsigned)f2bf(b) << 16);
}

__device__ __forceinline__ void fma8(float* acc, float w, uint4 u) {
    acc[0] += w * bflo(u.x); acc[1] += w * bfhi(u.x);
    acc[2] += w * bflo(u.y); acc[3] += w * bfhi(u.y);
    acc[4] += w * bflo(u.z); acc[5] += w * bfhi(u.z);
    acc[6] += w * bflo(u.w); acc[7] += w * bfhi(u.w);
}

// ---------------------------------------------------------------------------
// fp32 -> packed bf16x2 (n2 = number of float PAIRS)
__global__ void k_f2bf(const float* __restrict__ in, unsigned* __restrict__ out, int n2) {
    int i = blockIdx.x * blockDim.x + threadIdx.x;
    if (i < n2) {
        float2 v = ((const float2*)in)[i];
        out[i] = packbf2(v.x, v.y);
    }
}

// W1 [k][n] fp32 -> Wt [n][k] bf16  (transposed for MFMA B-frag contiguity)
__global__ void k_wt(const float* __restrict__ W, unsigned short* __restrict__ Wt) {
    int i = blockIdx.x * blockDim.x + threadIdx.x;   // 16384
    int k = i >> 7, n = i & 127;
    Wt[n * 128 + k] = f2bf(W[i]);
}

// ---------------------------------------------------------------------------
__global__ void k_count(const int* __restrict__ dst, int* __restrict__ indeg, int E) {
    int i = blockIdx.x * blockDim.x + threadIdx.x;
    if (i < E) atomicAdd(&indeg[dst[i]], 1);
}

__global__ void k_dinv(const int* __restrict__ indeg, float* __restrict__ dinv, int n) {
    int i = blockIdx.x * blockDim.x + threadIdx.x;
    if (i < n) dinv[i] = rsqrtf((float)(indeg[i] + 1));
}

__global__ void k_scan1(const int* __restrict__ in, int* __restrict__ out,
                        int* __restrict__ bsums, int n) {
    __shared__ int lds[256];
    int blk = blockIdx.x, t = threadIdx.x;
    int base = blk * SCAN_BLK + t * 4;
    int v[4];
#pragma unroll
    for (int i = 0; i < 4; ++i) v[i] = (base + i < n) ? in[base + i] : 0;
    int local = v[0] + v[1] + v[2] + v[3];
    lds[t] = local;
    __syncthreads();
    for (int off = 1; off < 256; off <<= 1) {
        int x = lds[t];
        int y = (t >= off) ? lds[t - off] : 0;
        __syncthreads();
        lds[t] = x + y;
        __syncthreads();
    }
    int excl = lds[t] - local;
    if (t == 255) bsums[blk] = lds[255];
    int run = excl;
#pragma unroll
    for (int i = 0; i < 4; ++i) {
        if (base + i < n) { out[base + i] = run; run += v[i]; }
    }
}

__global__ void k_scan2(int* __restrict__ bsums, int nb) {
    __shared__ int lds[256];
    int t = threadIdx.x;
    int orig = (t < nb) ? bsums[t] : 0;
    lds[t] = orig;
    __syncthreads();
    for (int off = 1; off < 256; off <<= 1) {
        int x = lds[t];
        int y = (t >= off) ? lds[t - off] : 0;
        __syncthreads();
        lds[t] = x + y;
        __syncthreads();
    }
    if (t < nb) bsums[t] = lds[t] - orig;
}

__global__ void k_scan3(int* __restrict__ rp, const int* __restrict__ boffs, int n, int E) {
    int i = blockIdx.x * blockDim.x + threadIdx.x;
    if (i < n) rp[i] += boffs[i / SCAN_BLK];
    if (i == n) rp[n] = E;
}

// fill CSR + per-edge normalized weight (kills the col->dinv dependent load)
__global__ void k_fill(const int* __restrict__ src, const int* __restrict__ dst,
                       const int* __restrict__ rp, int* __restrict__ cursor,
                       int* __restrict__ col, float* __restrict__ wgt,
                       const float* __restrict__ dinv, int E) {
    int i = blockIdx.x * blockDim.x + threadIdx.x;
    if (i < E) {
        int d = dst[i], s = src[i];
        int p = atomicAdd(&cursor[d], 1);
        int idx = rp[d] + p;
        col[idx] = s;
        wgt[idx] = dinv[d] * dinv[s];
    }
}

// ---------------------------------------------------------------------------
// gather-aggregate v3: wave = 4 groups x 16 lanes; each lane loads 16B (8 bf16),
// a group covers one 256B row, one load instruction fetches 4 edge rows.
// Virtual edge list per node: [self] + CSR edges; group g handles i = g, g+4, ...
// 2-deep software pipeline -> 8 rows in flight per wave.
#define AGG3_BODY(X2)                                                            \
    int lane = threadIdx.x & 63;                                                 \
    int grp  = lane >> 4;                                                        \
    int fl   = lane & 15;                                                        \
    int v = (blockIdx.x << 2) + (threadIdx.x >> 6);                              \
    if (v >= N_NODES) return;                                                    \
    float dv = dinv[v];                                                          \
    int e0 = rp[v];                                                              \
    int L  = rp[v + 1] - e0 + 1;    /* self + edges */                           \
    float acc[8] = {0.f,0.f,0.f,0.f,0.f,0.f,0.f,0.f};                            \
    int i = grp;                                                                 \
    int sA = -1, sB = -1; float wA = 0.f, wB = 0.f;                              \
    if (i < L) {                                                                 \
        if (i == 0) { sA = v; wA = dv * dv; }                                    \
        else        { sA = col[e0 + i - 1]; wA = wgt[e0 + i - 1]; }              \
    }                                                                            \
    if (i + 4 < L) { sB = col[e0 + i + 3]; wB = wgt[e0 + i + 3]; }               \
    while (sA >= 0) {                                                            \
        int sC = -1, sD = -1; float wC = 0.f, wD = 0.f;                          \
        if (i + 8  < L) { sC = col[e0 + i + 7];  wC = wgt[e0 + i + 7]; }         \
        if (i + 12 < L) { sD = col[e0 + i + 11]; wD = wgt[e0 + i + 11]; }        \
        uint4 uA = *(const uint4*)(X2 + (size_t)sA * 64 + fl * 4);               \
        uint4 uB;                                                                \
        bool hB = (sB >= 0);                                                     \
        if (hB) uB = *(const uint4*)(X2 + (size_t)sB * 64 + fl * 4);             \
        fma8(acc, wA, uA);                                                       \
        if (hB) fma8(acc, wB, uB);                                               \
        i += 8; sA = sC; wA = wC; sB = sD; wB = wD;                              \
    }                                                                            \
    _Pragma("unroll")                                                            \
    for (int j = 0; j < 8; ++j) {                                                \
        acc[j] += __shfl_xor(acc[j], 16, 64);                                    \
        acc[j] += __shfl_xor(acc[j], 32, 64);                                    \
    }

__global__ __launch_bounds__(256) void k_agg1(
    const unsigned* __restrict__ X2, unsigned* __restrict__ O2,
    const int* __restrict__ rp, const int* __restrict__ col,
    const float* __restrict__ wgt, const float* __restrict__ dinv)
{
    AGG3_BODY(X2)
    if (grp == 0) {
        uint4 o;
        o.x = packbf2(acc[0], acc[1]);
        o.y = packbf2(acc[2], acc[3]);
        o.z = packbf2(acc[4], acc[5]);
        o.w = packbf2(acc[6], acc[7]);
        *(uint4*)(O2 + (size_t)v * 64 + fl * 4) = o;
    }
}

__global__ __launch_bounds__(256) void k_agg2(
    const unsigned* __restrict__ X2,
    const int* __restrict__ rp, const int* __restrict__ col,
    const float* __restrict__ wgt, const float* __restrict__ dinv,
    const int* __restrict__ batch, float* __restrict__ P, int* __restrict__ cnt)
{
    AGG3_BODY(X2)
    int g = batch[v];
    // all lanes hold the full row after the butterfly; spread 128 atomics evenly
    atomicAdd(&P[(size_t)g * FDIM + fl * 8 + 2 * grp],     acc[2 * grp]);
    atomicAdd(&P[(size_t)g * FDIM + fl * 8 + 2 * grp + 1], acc[2 * grp + 1]);
    if (lane == 0) atomicAdd(&cnt[g], 1);
}

// ---------------------------------------------------------------------------
// B = relu(A @ W1 + b1) in bf16 via MFMA. Block = 64 rows; wave = 16 rows x 128 cols.
__global__ __launch_bounds__(256) void k_gemm_mfma(
    const unsigned short* __restrict__ A, const unsigned short* __restrict__ Wt,
    const float* __restrict__ bias, unsigned short* __restrict__ B)
{
    int lane = threadIdx.x & 63;
    int wv = threadIdx.x >> 6;
    size_t row0 = (size_t)blockIdx.x * 64 + (size_t)wv * 16;
    int r = lane & 15, g = lane >> 4;

    short8v af[4];
    const unsigned short* arow = A + (row0 + r) * FDIM + g * 8;
#pragma unroll
    for (int ks = 0; ks < 4; ++ks)
        af[ks] = *(const short8v*)(arow + ks * 32);

    f32x4 acc[8];
#pragma unroll
    for (int ct = 0; ct < 8; ++ct) {
        f32x4 a = {0.f, 0.f, 0.f, 0.f};
        const unsigned short* wrow = Wt + (ct * 16 + r) * FDIM + g * 8;
#pragma unroll
        for (int ks = 0; ks < 4; ++ks) {
            short8v bfr = *(const short8v*)(wrow + ks * 32);
            a = __builtin_amdgcn_mfma_f32_16x16x32_bf16(af[ks], bfr, a, 0, 0, 0);
        }
        acc[ct] = a;
    }

#pragma unroll
    for (int ct = 0; ct < 8; ++ct) {
        int c = ct * 16 + r;
        float bs = bias[c];
#pragma unroll
        for (int i = 0; i < 4; ++i) {
            size_t row = row0 + g * 4 + i;
            if (row < N_NODES) {
                float vv = fmaxf(acc[ct][i] + bs, 0.f);
                B[row * FDIM + c] = f2bf(vv);
            }
        }
    }
}

// ---------------------------------------------------------------------------
__global__ void k_wcomb(const float* __restrict__ W2, const float* __restrict__ Wf,
                        const float* __restrict__ b2, const float* __restrict__ bf,
                        float* __restrict__ Wc, float* __restrict__ bc) {
    int idx = blockIdx.x * blockDim.x + threadIdx.x;
    if (idx < 128 * 32) {
        int k = idx >> 5, c = idx & 31;
        float acc = 0.0f;
        for (int m = 0; m < 128; ++m) acc += W2[k * 128 + m] * Wf[m * 32 + c];
        Wc[idx] = acc;
    }
    if (idx < 32) {
        float acc = bf[idx];
        for (int m = 0; m < 128; ++m) acc += b2[m] * Wf[m * 32 + idx];
        bc[idx] = acc;
    }
}

__global__ void k_final(const float* __restrict__ P, const int* __restrict__ cnt,
                        const float* __restrict__ Wc, const float* __restrict__ bc,
                        const float* __restrict__ bf, float* __restrict__ out) {
    __shared__ float p[128];
    int g = blockIdx.x, t = threadIdx.x;
    int c_ = cnt[g];
    float inv = (c_ > 0) ? 1.0f / (float)c_ : 0.0f;
    p[t] = P[(size_t)g * FDIM + t] * inv;
    __syncthreads();
    if (t < N_CLASSES) {
        float acc = (c_ > 0) ? bc[t] : bf[t];
#pragma unroll
        for (int k = 0; k < 128; ++k) acc = fmaf(p[k], Wc[k * 32 + t], acc);
        out[(size_t)g * N_CLASSES + t] = acc;
    }
}

// ---------------------------------------------------------------------------
extern "C" void kernel_launch(void* const* d_in, const int* in_sizes, int n_in,
                              void* d_out, int out_size, void* d_ws, size_t ws_size,
                              hipStream_t stream) {
    const float* x    = (const float*)d_in[0];
    const int*   ei   = (const int*)d_in[1];
    const int*   batch= (const int*)d_in[2];
    const float* W1   = (const float*)d_in[3];
    const float* b1   = (const float*)d_in[4];
    const float* W2   = (const float*)d_in[5];
    const float* b2   = (const float*)d_in[6];
    const float* Wf   = (const float*)d_in[7];
    const float* bf   = (const float*)d_in[8];
    const int* src = ei;
    const int* dst = ei + N_EDGES;

    char* w = (char*)d_ws;
    auto alloc = [&](size_t bytes) { char* p = w; w += (bytes + 255) & ~255ull; return p; };
    int*      indeg  = (int*)     alloc((size_t)N_NODES * 4);
    float*    dinv   = (float*)   alloc((size_t)N_NODES * 4);
    int*      rp     = (int*)     alloc((size_t)(N_NODES + 1) * 4);
    int*      cursor = (int*)     alloc((size_t)N_NODES * 4);
    int*      bsums  = (int*)     alloc(1024 * 4);
    int*      col    = (int*)     alloc((size_t)N_EDGES * 4);
    float*    wgt    = (float*)   alloc((size_t)N_EDGES * 4);
    unsigned* xh     = (unsigned*)alloc((size_t)N_NODES * 64 * 4);   // bf16x2
    unsigned* Ab     = (unsigned*)alloc((size_t)M_PAD  * 64 * 4);    // bf16x2 (padded)
    unsigned* Bb     = (unsigned*)alloc((size_t)N_NODES * 64 * 4);   // bf16x2
    unsigned short* Wt = (unsigned short*)alloc(128 * 128 * 2);
    float*    P      = (float*)   alloc((size_t)N_GRAPHS * FDIM * 4);
    int*      cnt    = (int*)     alloc((size_t)N_GRAPHS * 4);
    float*    Wc     = (float*)   alloc(128 * 32 * 4);
    float*    bc     = (float*)   alloc(32 * 4);

    hipMemsetAsync(indeg,  0, (size_t)N_NODES * 4, stream);
    hipMemsetAsync(cursor, 0, (size_t)N_NODES * 4, stream);
    hipMemsetAsync(P,      0, (size_t)N_GRAPHS * FDIM * 4, stream);
    hipMemsetAsync(cnt,    0, (size_t)N_GRAPHS * 4, stream);

    const int nbScan = (N_NODES + SCAN_BLK - 1) / SCAN_BLK;   // 98

    // input conversions (independent of CSR build)
    k_f2bf<<<(N_NODES * 64 + 255) / 256, 256, 0, stream>>>(x, xh, N_NODES * 64);
    k_wt  <<<64, 256, 0, stream>>>(W1, Wt);

    // CSR build
    k_count<<<(N_EDGES + 255) / 256, 256, 0, stream>>>(dst, indeg, N_EDGES);
    k_dinv <<<(N_NODES + 255) / 256, 256, 0, stream>>>(indeg, dinv, N_NODES);
    k_scan1<<<nbScan, 256, 0, stream>>>(indeg, rp, bsums, N_NODES);
    k_scan2<<<1, 256, 0, stream>>>(bsums, nbScan);
    k_scan3<<<(N_NODES + 1 + 255) / 256, 256, 0, stream>>>(rp, bsums, N_NODES, N_EDGES);
    k_fill <<<(N_EDGES + 255) / 256, 256, 0, stream>>>(src, dst, rp, cursor, col, wgt, dinv, N_EDGES);

    // layer 1: aggregate (bf16 gather) then MFMA GEMM + bias + relu
    k_agg1<<<(N_NODES + 3) / 4, 256, 0, stream>>>(xh, Ab, rp, col, wgt, dinv);
    k_gemm_mfma<<<M_PAD / 64, 256, 0, stream>>>((const unsigned short*)Ab, Wt, b1,
                                                (unsigned short*)Bb);

    // classifier weight folding (tiny, independent)
    k_wcomb<<<16, 256, 0, stream>>>(W2, Wf, b2, bf, Wc, bc);

    // layer 2 aggregation fused with mean-pool accumulation
    k_agg2<<<(N_NODES + 3) / 4, 256, 0, stream>>>(Bb, rp, col, wgt, dinv, batch, P, cnt);

    // final: mean, fold through Wc=W2@Wf, write [1024,32]
    k_final<<<N_GRAPHS, 128, 0, stream>>>(P, cnt, Wc, bc, bf, (float*)d_out);
}